// Round 1
// baseline (861.935 us; speedup 1.0000x reference)
//
#include <hip/hip_runtime.h>

#define B_   8
#define C_   64
#define O_   64
#define H_   512
#define Wd_  512
#define SEG_ 4
#define HS_  128   // H / SEG
#define WS_  128   // Wd / SEG

// ---------------------------------------------------------------------------
// Kernel 1: segment mean-pool.
// Grid: B*C*SEG blocks; block (b,c,i) reduces rows [i*128, i*128+128) of the
// (b,c) 512x512 channel image (a contiguous 128*512-float region) into 4
// column-segment sums. With float4 loads and a stride-256 loop, (f & 127) is
// per-thread invariant => each thread's column segment j is FIXED, so one
// accumulator per thread suffices.
// ---------------------------------------------------------------------------
__global__ __launch_bounds__(256) void pool_kernel(const float* __restrict__ x,
                                                   float* __restrict__ pooled) {
    const int blk = blockIdx.x;      // ((b*C + c)*SEG + i)
    const int i   = blk & 3;
    const int bc  = blk >> 2;        // b*C + c
    const float4* base =
        (const float4*)(x + ((size_t)bc * H_ + (size_t)i * HS_) * Wd_);

    const int tid = threadIdx.x;
    float sum = 0.f;
    // 128*512/4 = 16384 float4s, 64 per thread
    #pragma unroll 8
    for (int f = tid; f < HS_ * Wd_ / 4; f += 256) {
        float4 v = base[f];
        sum += (v.x + v.y) + (v.z + v.w);
    }

    // j = ((f*4) & 511) >> 7 = (tid & 127) >> 5 : constant per thread.
    // Reduce within each 32-lane group (all share the same j).
    for (int off = 16; off >= 1; off >>= 1)
        sum += __shfl_down(sum, off, 32);

    __shared__ float sums[8];        // 8 groups of 32; group g has j = g & 3
    const int g = tid >> 5;
    if ((tid & 31) == 0) sums[g] = sum;
    __syncthreads();

    if (tid < 4) {
        float total = sums[tid] + sums[tid + 4];   // groups g and g+4 share j
        pooled[(size_t)blk * 4 + tid] = total * (1.0f / (HS_ * WS_));
    }
}

// ---------------------------------------------------------------------------
// Kernel 2: tiny per-tile linear + bias + seg_w scale.
// weighted[b][o][i][j] = (sum_c pooled[b][c][i][j] * W[o][c] + bias[o]) * seg_w[i][j]
// 8192 outputs, each a length-64 dot product. Trivial compute.
// ---------------------------------------------------------------------------
__global__ __launch_bounds__(256) void linear_kernel(const float* __restrict__ pooled,
                                                     const float* __restrict__ Wm,
                                                     const float* __restrict__ bias,
                                                     const float* __restrict__ seg_w,
                                                     float* __restrict__ weighted) {
    const int idx = blockIdx.x * 256 + threadIdx.x;   // [B][O][4][4]
    if (idx >= B_ * O_ * 16) return;
    const int ij = idx & 15;
    const int o  = (idx >> 4) & (O_ - 1);
    const int b  = idx >> 10;

    const float* pp = pooled + (size_t)b * C_ * 16 + ij;   // stride 16 over c
    const float* wr = Wm + (size_t)o * C_;
    float acc = 0.f;
    #pragma unroll 16
    for (int c = 0; c < C_; ++c)
        acc += pp[c * 16] * wr[c];

    weighted[idx] = (acc + bias[o]) * seg_w[ij];
}

// ---------------------------------------------------------------------------
// Kernel 3: broadcast each tile value over its 128x128 block.
// Grid: B*O*SEG blocks; block (b,o,i) fills rows [i*128, i*128+128) of the
// (b,o) output image. Same (tid & 127) invariance => value is uniform per
// thread; 64 coalesced float4 stores per thread.
// ---------------------------------------------------------------------------
__global__ __launch_bounds__(256) void bcast_kernel(const float* __restrict__ weighted,
                                                    float* __restrict__ out) {
    const int blk = blockIdx.x;      // ((b*O + o)*SEG + i)
    const int i   = blk & 3;
    const int bo  = blk >> 2;        // b*O + o
    const float* wv = weighted + (size_t)bo * 16 + (size_t)i * 4;

    const int tid = threadIdx.x;
    const int j   = (tid & 127) >> 5;
    const float v = wv[j];
    const float4 vv = make_float4(v, v, v, v);

    float4* base = (float4*)(out + ((size_t)bo * H_ + (size_t)i * HS_) * Wd_);
    #pragma unroll 8
    for (int f = tid; f < HS_ * Wd_ / 4; f += 256)
        base[f] = vv;
}

extern "C" void kernel_launch(void* const* d_in, const int* in_sizes, int n_in,
                              void* d_out, int out_size, void* d_ws, size_t ws_size,
                              hipStream_t stream) {
    const float* x     = (const float*)d_in[0];
    const float* Wm    = (const float*)d_in[1];
    const float* bias  = (const float*)d_in[2];
    const float* seg_w = (const float*)d_in[3];
    float* out = (float*)d_out;

    float* pooled   = (float*)d_ws;                 // B*C*16  = 8192 floats
    float* weighted = pooled + (size_t)B_ * C_ * 16; // B*O*16 = 8192 floats

    pool_kernel<<<B_ * C_ * SEG_, 256, 0, stream>>>(x, pooled);
    linear_kernel<<<(B_ * O_ * 16 + 255) / 256, 256, 0, stream>>>(
        pooled, Wm, bias, seg_w, weighted);
    bcast_kernel<<<B_ * O_ * SEG_, 256, 0, stream>>>(weighted, out);
}